// Round 8
// baseline (174.374 us; speedup 1.0000x reference)
//
#include <hip/hip_runtime.h>

// GCN3: bucket-partition edges -> per-bucket counting sort -> CSR, then
// atomic-free register-accumulating gathers fused with the dense transforms.
// Feature tables (x, h1, t3) stored as bf16; fp32 math. Gathers process TWO
// nodes per 32-lane group with interleaved 8-deep load streams to double the
// number of independent memory chains per lane (latency hiding).

#define RANGE_BITS 7
#define RANGE      128
#define MAXBK      1024
#define CHUNK      8192
#define FILL_T     512
#define CSR_T      256
#define CSR_CAP    4096

typedef unsigned short ushort_t;

__device__ __forceinline__ ushort_t f32_to_bf16(float x) {
    unsigned u = __float_as_uint(x);
    u += 0x7fffu + ((u >> 16) & 1u);    // RNE
    return (ushort_t)(u >> 16);
}
__device__ __forceinline__ float bf16_to_f32(ushort_t h) {
    return __uint_as_float(((unsigned)h) << 16);
}

// ---------------- partition build ----------------

__global__ void hist_kernel(const int* __restrict__ dst, int* __restrict__ ghist,
                            int nE, int nbk) {
    __shared__ int h[MAXBK];
    const int tid = threadIdx.x;
    for (int i = tid; i < nbk; i += blockDim.x) h[i] = 0;
    __syncthreads();
    const int stride = gridDim.x * blockDim.x;
    for (int e = blockIdx.x * blockDim.x + tid; e < nE; e += stride)
        atomicAdd(&h[dst[e] >> RANGE_BITS], 1);
    __syncthreads();
    for (int i = tid; i < nbk; i += blockDim.x) {
        int c = h[i];
        if (c) atomicAdd(&ghist[i], c);
    }
}

__global__ void scan_kernel(int* __restrict__ ghist, int* __restrict__ boff,
                            int* __restrict__ gcur, int nbk) {
    __shared__ int lds[MAXBK];
    const int tid = threadIdx.x;
    for (int i = tid; i < nbk; i += blockDim.x) lds[i] = ghist[i];
    __syncthreads();
    for (int o = 1; o < nbk; o <<= 1) {
        int v = (tid >= o && tid < nbk) ? lds[tid - o] : 0;
        __syncthreads();
        if (tid < nbk) lds[tid] += v;
        __syncthreads();
    }
    if (tid < nbk) {
        int ex = (tid == 0) ? 0 : lds[tid - 1];
        boff[tid] = ex;
        gcur[tid] = ex;
        if (tid == nbk - 1) boff[nbk] = lds[tid];
    }
}

__global__ __launch_bounds__(FILL_T)
void fill_kernel(const int* __restrict__ src, const int* __restrict__ dst,
                 int* __restrict__ gcur, unsigned* __restrict__ edata,
                 int nE, int nbk) {
    __shared__ int cnt[MAXBK];
    __shared__ int base[MAXBK];
    const int tid = threadIdx.x;
    const int c0 = blockIdx.x * CHUNK;
    const int c1 = min(c0 + CHUNK, nE);
    for (int i = tid; i < nbk; i += FILL_T) cnt[i] = 0;
    __syncthreads();
    for (int e = c0 + tid; e < c1; e += FILL_T)
        atomicAdd(&cnt[dst[e] >> RANGE_BITS], 1);
    __syncthreads();
    for (int i = tid; i < nbk; i += FILL_T) {
        int c = cnt[i];
        base[i] = c ? atomicAdd(&gcur[i], c) : 0;
        cnt[i] = 0;
    }
    __syncthreads();
    for (int e = c0 + tid; e < c1; e += FILL_T) {
        int d = dst[e];
        int bk = d >> RANGE_BITS;
        int pos = base[bk] + atomicAdd(&cnt[bk], 1);
        edata[pos] = ((unsigned)(d & (RANGE - 1)) << 17) | (unsigned)src[e];
    }
}

__global__ __launch_bounds__(CSR_T)
void csr_kernel(const unsigned* __restrict__ edata, const int* __restrict__ boff,
                int* __restrict__ off, int* __restrict__ perm, int n, int nE) {
    __shared__ int hist[RANGE];
    __shared__ int loff[RANGE];
    __shared__ int cur[RANGE];
    __shared__ unsigned stage[CSR_CAP];
    const int tid = threadIdx.x;
    const int rid = blockIdx.x;
    const int e0  = boff[rid];
    const int cnt = boff[rid + 1] - e0;
    const bool fits = cnt <= CSR_CAP;

    if (tid < RANGE) hist[tid] = 0;
    __syncthreads();
    for (int i = tid; i < cnt; i += CSR_T) {
        unsigned p = edata[e0 + i];
        if (fits) stage[i] = p;
        atomicAdd(&hist[p >> 17], 1);
    }
    __syncthreads();
    if (tid < RANGE) loff[tid] = hist[tid];
    __syncthreads();
    for (int o = 1; o < RANGE; o <<= 1) {
        int v = (tid >= o && tid < RANGE) ? loff[tid - o] : 0;
        __syncthreads();
        if (tid < RANGE) loff[tid] += v;
        __syncthreads();
    }
    if (tid < RANGE) {
        int ex = loff[tid] - hist[tid];
        cur[tid] = ex;
        int node = (rid << RANGE_BITS) + tid;
        if (node < n) off[node] = e0 + ex;
    }
    if (tid == 0 && rid == gridDim.x - 1) off[n] = nE;
    __syncthreads();
    for (int i = tid; i < cnt; i += CSR_T) {
        unsigned p = fits ? stage[i] : edata[e0 + i];
        int pos = atomicAdd(&cur[p >> 17], 1);
        perm[e0 + pos] = (int)(p & 0x1ffffu);
    }
}

// ---------------- fp32 -> bf16 table convert ----------------

__global__ void cvt_bf16_kernel(const float* __restrict__ in,
                                ushort_t* __restrict__ out, int total8) {
    int i = blockIdx.x * blockDim.x + threadIdx.x;
    if (i >= total8) return;
    const float4* rp = (const float4*)(in + (size_t)i * 8);
    float4 a = rp[0], b = rp[1];
    uint4 v;
    v.x = (unsigned)f32_to_bf16(a.x) | ((unsigned)f32_to_bf16(a.y) << 16);
    v.y = (unsigned)f32_to_bf16(a.z) | ((unsigned)f32_to_bf16(a.w) << 16);
    v.z = (unsigned)f32_to_bf16(b.x) | ((unsigned)f32_to_bf16(b.y) << 16);
    v.w = (unsigned)f32_to_bf16(b.z) | ((unsigned)f32_to_bf16(b.w) << 16);
    ((uint4*)(out + (size_t)i * 8))[0] = v;
}

// ---------------- fused gather + dense (2 nodes / 32-lane group) ----------------

template <bool FUSE3>
__global__ __launch_bounds__(256)
void gather_dense_kernel(const ushort_t* __restrict__ t,   // [n][32] bf16
                         const int* __restrict__ perm,
                         const int* __restrict__ off,
                         const float* __restrict__ W,      // [32][32]
                         const float* __restrict__ b,      // [32]
                         const float* __restrict__ W3,     // [32][16] (FUSE3)
                         ushort_t* __restrict__ out,       // bf16
                         int n) {
    __shared__ float rowbuf[8][33];
    __shared__ float rowbuf2[8][33];
    __shared__ float sW3[32 * 16];
    if (FUSE3) {
        for (int i = threadIdx.x; i < 32 * 16; i += 256) sW3[i] = W3[i];
        __syncthreads();
    }

    const int gid   = blockIdx.x * 256 + threadIdx.x;
    const int pair  = gid >> 5;
    const int f     = gid & 31;
    const int g     = threadIdx.x >> 5;
    const int nodeA = pair * 2;
    const int nodeB = nodeA + 1;
    if (nodeA >= n) return;
    const bool hasB = nodeB < n;

    const int oA = off[nodeA];
    const int dA = off[nodeA + 1] - oA;
    const int oB = hasB ? off[nodeB] : 0;
    const int dB = hasB ? off[nodeB + 1] - oB : 0;
    const int* __restrict__ ppA = perm + oA;
    const int* __restrict__ ppB = perm + oB;

    float accA = 0.0f, accB = 0.0f;
    const int dmax = dA > dB ? dA : dB;
    for (int base = 0; base < dmax; base += 32) {
        int mA = dA - base; mA = mA < 0 ? 0 : (mA > 32 ? 32 : mA);
        int mB = dB - base; mB = mB < 0 ? 0 : (mB > 32 ? 32 : mB);
        int pA = (f < mA) ? ppA[base + f] : 0;
        int pB = (f < mB) ? ppB[base + f] : 0;
        const int mm = mA < mB ? mA : mB;
        int i = 0;
        // interleaved dual-stream 8-deep: 16 independent loads in flight
        for (; i + 7 < mm; i += 8) {
            int sA[8], sB[8]; ushort_t vA[8], vB[8];
#pragma unroll
            for (int u = 0; u < 8; ++u) { sA[u] = __shfl(pA, i + u, 32);
                                          sB[u] = __shfl(pB, i + u, 32); }
#pragma unroll
            for (int u = 0; u < 8; ++u) { vA[u] = t[(sA[u] << 5) + f];
                                          vB[u] = t[(sB[u] << 5) + f]; }
#pragma unroll
            for (int u = 0; u < 8; ++u) { accA += bf16_to_f32(vA[u]);
                                          accB += bf16_to_f32(vB[u]); }
        }
        int iB = i;
        // A remainder
        for (; i + 7 < mA; i += 8) {
            int s[8]; ushort_t v[8];
#pragma unroll
            for (int u = 0; u < 8; ++u) s[u] = __shfl(pA, i + u, 32);
#pragma unroll
            for (int u = 0; u < 8; ++u) v[u] = t[(s[u] << 5) + f];
#pragma unroll
            for (int u = 0; u < 8; ++u) accA += bf16_to_f32(v[u]);
        }
        for (; i + 3 < mA; i += 4) {
            int s[4]; ushort_t v[4];
#pragma unroll
            for (int u = 0; u < 4; ++u) s[u] = __shfl(pA, i + u, 32);
#pragma unroll
            for (int u = 0; u < 4; ++u) v[u] = t[(s[u] << 5) + f];
#pragma unroll
            for (int u = 0; u < 4; ++u) accA += bf16_to_f32(v[u]);
        }
        for (; i < mA; ++i) accA += bf16_to_f32(t[(__shfl(pA, i, 32) << 5) + f]);
        // B remainder
        for (; iB + 7 < mB; iB += 8) {
            int s[8]; ushort_t v[8];
#pragma unroll
            for (int u = 0; u < 8; ++u) s[u] = __shfl(pB, iB + u, 32);
#pragma unroll
            for (int u = 0; u < 8; ++u) v[u] = t[(s[u] << 5) + f];
#pragma unroll
            for (int u = 0; u < 8; ++u) accB += bf16_to_f32(v[u]);
        }
        for (; iB + 3 < mB; iB += 4) {
            int s[4]; ushort_t v[4];
#pragma unroll
            for (int u = 0; u < 4; ++u) s[u] = __shfl(pB, iB + u, 32);
#pragma unroll
            for (int u = 0; u < 4; ++u) v[u] = t[(s[u] << 5) + f];
#pragma unroll
            for (int u = 0; u < 4; ++u) accB += bf16_to_f32(v[u]);
        }
        for (; iB < mB; ++iB) accB += bf16_to_f32(t[(__shfl(pB, iB, 32) << 5) + f]);
    }

    // ---- dense epilogue, node A then node B (wave-lockstep LDS exchange) ----
    rowbuf[g][f] = accA;
    float rA = b[f];
#pragma unroll
    for (int k = 0; k < 32; ++k) rA += rowbuf[g][k] * W[(k << 5) + f];
    rA = rA >= 0.0f ? rA : 0.1f * rA;

    rowbuf[g][f] = accB;
    float rB = b[f];
#pragma unroll
    for (int k = 0; k < 32; ++k) rB += rowbuf[g][k] * W[(k << 5) + f];
    rB = rB >= 0.0f ? rB : 0.1f * rB;

    if (!FUSE3) {
        out[(nodeA << 5) + f] = f32_to_bf16(rA);
        if (hasB) out[(nodeB << 5) + f] = f32_to_bf16(rB);
    } else {
        const int j = f & 15;
        rowbuf2[g][f] = rA;
        float t3A = 0.0f;
#pragma unroll
        for (int k = 0; k < 32; ++k) t3A += rowbuf2[g][k] * sW3[(k << 4) + j];
        rowbuf2[g][f] = rB;
        float t3B = 0.0f;
#pragma unroll
        for (int k = 0; k < 32; ++k) t3B += rowbuf2[g][k] * sW3[(k << 4) + j];
        if (f < 16) {
            out[(nodeA << 4) + f] = f32_to_bf16(t3A);
            if (hasB) out[(nodeB << 4) + f] = f32_to_bf16(t3B);
        }
    }
}

// layer 3: 16-wide gather, 2 nodes per 16-lane group, fp32 output
__global__ __launch_bounds__(256)
void gather16_kernel(const ushort_t* __restrict__ t3,     // [n][16] bf16
                     const int* __restrict__ perm,
                     const int* __restrict__ off,
                     const float* __restrict__ b,         // [16]
                     float* __restrict__ out,             // [n][16] fp32
                     int n) {
    const int gid   = blockIdx.x * 256 + threadIdx.x;
    const int pair  = gid >> 4;
    const int j     = gid & 15;
    const int nodeA = pair * 2;
    const int nodeB = nodeA + 1;
    if (nodeA >= n) return;
    const bool hasB = nodeB < n;

    const int oA = off[nodeA];
    const int dA = off[nodeA + 1] - oA;
    const int oB = hasB ? off[nodeB] : 0;
    const int dB = hasB ? off[nodeB + 1] - oB : 0;
    const int* __restrict__ ppA = perm + oA;
    const int* __restrict__ ppB = perm + oB;

    float accA = b[j], accB = b[j];
    const int dmax = dA > dB ? dA : dB;
    for (int base = 0; base < dmax; base += 16) {
        int mA = dA - base; mA = mA < 0 ? 0 : (mA > 16 ? 16 : mA);
        int mB = dB - base; mB = mB < 0 ? 0 : (mB > 16 ? 16 : mB);
        int pA = (j < mA) ? ppA[base + j] : 0;
        int pB = (j < mB) ? ppB[base + j] : 0;
        const int mm = mA < mB ? mA : mB;
        int i = 0;
        for (; i + 7 < mm; i += 8) {
            int sA[8], sB[8]; ushort_t vA[8], vB[8];
#pragma unroll
            for (int u = 0; u < 8; ++u) { sA[u] = __shfl(pA, i + u, 16);
                                          sB[u] = __shfl(pB, i + u, 16); }
#pragma unroll
            for (int u = 0; u < 8; ++u) { vA[u] = t3[(sA[u] << 4) + j];
                                          vB[u] = t3[(sB[u] << 4) + j]; }
#pragma unroll
            for (int u = 0; u < 8; ++u) { accA += bf16_to_f32(vA[u]);
                                          accB += bf16_to_f32(vB[u]); }
        }
        int iB = i;
        for (; i < mA; ++i) accA += bf16_to_f32(t3[(__shfl(pA, i, 16) << 4) + j]);
        for (; iB < mB; ++iB) accB += bf16_to_f32(t3[(__shfl(pB, iB, 16) << 4) + j]);
    }
    out[(nodeA << 4) + j] = accA;
    if (hasB) out[(nodeB << 4) + j] = accB;
}

// ---------------- fallback: atomic scatter path (fp32) ----------------

template <int F>
__global__ void scatter_kernel(const float* __restrict__ h, const int* __restrict__ src,
                               const int* __restrict__ dst, float* __restrict__ agg,
                               int n_edges) {
    int gid = blockIdx.x * blockDim.x + threadIdx.x;
    int e = gid / F, f = gid & (F - 1);
    if (e >= n_edges) return;
    unsafeAtomicAdd(&agg[(size_t)dst[e] * F + f], h[(size_t)src[e] * F + f]);
}

template <int IN, int OUT, bool RELU>
__global__ void dense_bias_kernel(const float* __restrict__ in, const float* __restrict__ W,
                                  const float* __restrict__ b, float* __restrict__ out, int n) {
    __shared__ float sW[IN * OUT];
    __shared__ float sb[OUT];
    for (int i = threadIdx.x; i < IN * OUT; i += blockDim.x) sW[i] = W[i];
    for (int i = threadIdx.x; i < OUT; i += blockDim.x) sb[i] = b[i];
    __syncthreads();
    int node = blockIdx.x * blockDim.x + threadIdx.x;
    if (node >= n) return;
    float acc[OUT];
#pragma unroll
    for (int j = 0; j < OUT; ++j) acc[j] = sb[j];
#pragma unroll
    for (int k = 0; k < IN; ++k) {
        float a = in[(size_t)node * IN + k];
#pragma unroll
        for (int j = 0; j < OUT; ++j) acc[j] += a * sW[k * OUT + j];
    }
#pragma unroll
    for (int j = 0; j < OUT; ++j) {
        float v = acc[j];
        out[(size_t)node * OUT + j] = (RELU && v < 0.0f) ? 0.1f * v : v;
    }
}

template <int IN, int OUT>
__global__ void dense_kernel(const float* __restrict__ in, const float* __restrict__ W,
                             float* __restrict__ out, int n) {
    __shared__ float sW[IN * OUT];
    for (int i = threadIdx.x; i < IN * OUT; i += blockDim.x) sW[i] = W[i];
    __syncthreads();
    int node = blockIdx.x * blockDim.x + threadIdx.x;
    if (node >= n) return;
    float acc[OUT];
#pragma unroll
    for (int j = 0; j < OUT; ++j) acc[j] = 0.0f;
#pragma unroll
    for (int k = 0; k < IN; ++k) {
        float a = in[(size_t)node * IN + k];
#pragma unroll
        for (int j = 0; j < OUT; ++j) acc[j] += a * sW[k * OUT + j];
    }
#pragma unroll
    for (int j = 0; j < OUT; ++j) out[(size_t)node * OUT + j] = acc[j];
}

__global__ void init_out_kernel(float* __restrict__ out, const float* __restrict__ b,
                                int total) {
    int gid = blockIdx.x * blockDim.x + threadIdx.x;
    if (gid < total) out[gid] = b[gid & 15];
}

// ---------------- launch ----------------

extern "C" void kernel_launch(void* const* d_in, const int* in_sizes, int n_in,
                              void* d_out, int out_size, void* d_ws, size_t ws_size,
                              hipStream_t stream) {
    const float* x  = (const float*)d_in[0];
    const int* src  = (const int*)d_in[1];
    const int* dst  = (const int*)d_in[2];
    const float* W1 = (const float*)d_in[3];
    const float* b1 = (const float*)d_in[4];
    const float* W2 = (const float*)d_in[5];
    const float* b2 = (const float*)d_in[6];
    const float* W3 = (const float*)d_in[7];
    const float* b3 = (const float*)d_in[8];
    float* out = (float*)d_out;

    const int n  = in_sizes[0] / 32;    // 100000
    const int nE = in_sizes[1];         // 1600000
    const int nbk = (n + RANGE - 1) >> RANGE_BITS;   // 782

    unsigned* wsw   = (unsigned*)d_ws;
    ushort_t* xb    = (ushort_t*)wsw;                      // n*32 bf16
    ushort_t* h1b   = (ushort_t*)(wsw + (size_t)n * 16);   // n*32 bf16
    ushort_t* t3b   = (ushort_t*)(wsw + (size_t)n * 32);   // n*16 bf16
    unsigned* edata = wsw + (size_t)n * 40;                // nE
    int*      perm  = (int*)(edata + nE);                  // nE
    int*      off   = perm + nE;                           // n+1
    int*      boff  = off + n + 1;                         // nbk+1
    int*      gcur  = boff + nbk + 1;                      // nbk
    size_t need = ((size_t)n * 40 + 2 * (size_t)nE + (size_t)n + 2 * (size_t)nbk + 2) * 4;

    if (ws_size >= need && nbk <= MAXBK && n < (1 << 17) && (n * 32) % 8 == 0) {
        hipMemsetAsync(gcur, 0, (size_t)nbk * sizeof(int), stream);
        hist_kernel<<<256, 512, 0, stream>>>(dst, gcur, nE, nbk);
        cvt_bf16_kernel<<<(n * 32 / 8 + 255) / 256, 256, 0, stream>>>(x, xb, n * 32 / 8);
        scan_kernel<<<1, 1024, 0, stream>>>(gcur, boff, gcur, nbk);
        fill_kernel<<<(nE + CHUNK - 1) / CHUNK, FILL_T, 0, stream>>>(src, dst, gcur, edata, nE, nbk);
        csr_kernel<<<nbk, CSR_T, 0, stream>>>(edata, boff, off, perm, n, nE);

        const int npair = (n + 1) / 2;
        const int g32 = (npair * 32 + 255) / 256;
        const int g16 = (npair * 16 + 255) / 256;
        gather_dense_kernel<false><<<g32, 256, 0, stream>>>(xb, perm, off, W1, b1, nullptr, h1b, n);
        gather_dense_kernel<true><<<g32, 256, 0, stream>>>(h1b, perm, off, W2, b2, W3, t3b, n);
        gather16_kernel<<<g16, 256, 0, stream>>>(t3b, perm, off, b3, out, n);
    } else {
        const int BLK = 256;
        const int node_grid = (n + BLK - 1) / BLK;
        float* agg = (float*)d_ws;
        float* h   = agg + (size_t)n * 32;
        hipMemsetAsync(agg, 0, (size_t)n * 32 * sizeof(float), stream);
        scatter_kernel<32><<<((size_t)nE * 32 + BLK - 1) / BLK, BLK, 0, stream>>>(x, src, dst, agg, nE);
        dense_bias_kernel<32, 32, true><<<node_grid, BLK, 0, stream>>>(agg, W1, b1, h, n);
        hipMemsetAsync(agg, 0, (size_t)n * 32 * sizeof(float), stream);
        scatter_kernel<32><<<((size_t)nE * 32 + BLK - 1) / BLK, BLK, 0, stream>>>(h, src, dst, agg, nE);
        dense_bias_kernel<32, 32, true><<<node_grid, BLK, 0, stream>>>(agg, W2, b2, h, n);
        dense_kernel<32, 16><<<node_grid, BLK, 0, stream>>>(h, W3, agg, n);
        init_out_kernel<<<(n * 16 + BLK - 1) / BLK, BLK, 0, stream>>>(out, b3, n * 16);
        scatter_kernel<16><<<((size_t)nE * 16 + BLK - 1) / BLK, BLK, 0, stream>>>(agg, src, dst, out, nE);
    }
}